// Round 11
// baseline (217.860 us; speedup 1.0000x reference)
//
#include <hip/hip_runtime.h>
#include <hip/hip_bf16.h>

typedef __bf16 bf16x8_t __attribute__((ext_vector_type(8)));
typedef float floatx4_t __attribute__((ext_vector_type(4)));

#define H 128
#define BATCH 256
#define SEQ 1024
#define NROWS_TOTAL (BATCH * SEQ)            // 262144 rows of x
#define STEP_ELEMS 33521664.0f               // 256*1023*128
#define GRID 1024
#define NTILES 16384                         // 16-row tiles

// ws layout: [0, 32768)      : Dpack, bf16, MFMA-B-fragment order [kt][n][lane][j]
//            [32768, 32776)  : accum[0]=step_sum, accum[1]=l2_sum
//            [65536, 131072) : T = A*A, fp32 row-major
//
// Algebra: f(y)=y@C.T is linear, so RK4 collapses to y1 = y·(I + D),
// D = A + A^2/2 + A^3/6 + A^4/24, A = C^T (truncated expm). Main pass is one
// streaming GEMM P = y·D (bf16 MFMA correction; residual (y-x1) exact fp32).
// v11: CONVOY-SHRINK variant of v4. v4-class main (~54 us) shows all pipes
// idle (VALU 7%, MFMA 3%, HBM 10%) -> stall-bound on 8-wave barrier convoys
// with only 2 independent blocks/CU. Now: 256-thr/4-wave blocks, 16-row
// tiles, (256,4) -> 4 independent blocks/CU, barrier population halved,
// live-set ~90 VGPR (no v7/v8-style spill). Epilogue = v8's (validated),
// staging map = v4's (validated). Separate finalize (R9: fused fence = +46us).

// ---- prep stage 1: T = A*A (A = C^T), plus l2 term and accumulator init ----
__global__ __launch_bounds__(256) void prep_p1(const float* __restrict__ C,
                                               float* __restrict__ T,
                                               float* __restrict__ accum) {
  int e = blockIdx.x * 256 + threadIdx.x;    // 64 WGs * 256 = 16384 elements
  int i = e >> 7, j = e & 127;
  const float* Ci = C + i;                   // C[k][i], stride H — wave-broadcast
  const float* Cj = C + j * H;               // own row, stride 1
  float s = 0.f;
  #pragma unroll 8
  for (int k = 0; k < H; k++) s += Ci[k * H] * Cj[k];
  T[e] = s;

  if (blockIdx.x == 0) {
    float l2 = 0.f;
    for (int q = threadIdx.x; q < H * H; q += 256) {
      float c = C[q], c2 = c * c;
      l2 += c2 * c2;                         // sum C^4
    }
    #pragma unroll
    for (int off = 32; off > 0; off >>= 1) l2 += __shfl_down(l2, off);
    __shared__ float red[4];
    if ((threadIdx.x & 63) == 0) red[threadIdx.x >> 6] = l2;
    __syncthreads();
    if (threadIdx.x == 0) {
      accum[0] = 0.f;
      accum[1] = red[0] + red[1] + red[2] + red[3];
    }
  }
}

// ---- prep stage 2: D = A + T/2 + (T*A)/6 + (T*T)/24, packed to MFMA B-frag layout ----
__global__ __launch_bounds__(256) void prep_p2(const float* __restrict__ C,
                                               const float* __restrict__ T,
                                               __bf16* __restrict__ Dpack) {
  int e = blockIdx.x * 256 + threadIdx.x;
  int i = e >> 7, j = e & 127;
  const float* Ti = T + i * H;               // wave-broadcast row
  const float* Cj = C + j * H;               // own row
  const float* Tj = T + j;                   // column — L2-resident
  float s3 = 0.f, s4 = 0.f;
  #pragma unroll 8
  for (int k = 0; k < H; k++) {
    float t = Ti[k];
    s3 += t * Cj[k];
    s4 += t * Tj[k * H];
  }
  float d = C[j * H + i] + 0.5f * Ti[j] + s3 * (1.f / 6.f) + s4 * (1.f / 24.f);
  // pack: frag(kt,n), lane lanep, elem je holds D[kt*32 + (lanep>>4)*8 + je][n*16 + (lanep&15)]
  int kt = i >> 5, lq = (i >> 3) & 3, je = i & 7;
  int n = j >> 4, mm = j & 15;
  int lanep = lq * 16 + mm;
  Dpack[(size_t)(((kt * 8 + n) * 64 + lanep) * 8 + je)] = (__bf16)d;
}

// ---- main streaming pass: P = y*D via MFMA, residual + square + reduce ----
// 256 threads = 4 waves; 16-row tiles; wave w owns output cols [32w, 32w+32).
__global__ __launch_bounds__(256, 4) void sindy_main(const float* __restrict__ x,
                                                     const __bf16* __restrict__ Dpack,
                                                     float* __restrict__ accum) {
  // 16-row x-tile as bf16 MFMA-A fragments: [kt][lane][j], 4 KB, linear
  // per-lane frag addressing -> conflict-free b128 LDS reads
  __shared__ __align__(16) __bf16 Atile[4][64][8];

  int tid = threadIdx.x;
  int lane = tid & 63;
  int wave = tid >> 6;                       // 0..3: cols [32*wave, +32)
  int m = lane & 15, quad = lane >> 4;

  // B fragments for this wave's 32-col strip: 8 frags = 32 VGPRs
  bf16x8_t breg[2][4];
  const bf16x8_t* Dp = (const bf16x8_t*)Dpack;
  #pragma unroll
  for (int n2 = 0; n2 < 2; n2++)
    #pragma unroll
    for (int kt = 0; kt < 4; kt++)
      breg[n2][kt] = Dp[(kt * 8 + wave * 2 + n2) * 64 + lane];

  // staging coords: thread t loads row (t>>4), 8-col group (t&15)
  // (threads 0-15 cover row 0 fully -> coalesced 512B per 16 threads)
  int row_st = tid >> 4;                     // 0..15
  int c8 = (tid & 15) << 3;                  // 0,8,..,120
  int kt_st = (tid & 15) >> 2;               // c8>>5
  int lanep_st = row_st + ((tid & 3) << 4);  // row + 16*((c8>>3)&3)

  float lsum = 0.f;

  for (int rt = blockIdx.x; rt < NTILES; rt += GRID) {
    size_t row0 = (size_t)rt << 4;           // global first row of tile

    // ---- stage: 16x128 fp32 -> bf16 A-frags in LDS ----
    {
      const float* src = x + ((row0 + row_st) << 7) + c8;
      floatx4_t u0 = *(const floatx4_t*)(src);
      floatx4_t u1 = *(const floatx4_t*)(src + 4);
      bf16x8_t f0;
      f0[0] = (__bf16)u0[0]; f0[1] = (__bf16)u0[1]; f0[2] = (__bf16)u0[2]; f0[3] = (__bf16)u0[3];
      f0[4] = (__bf16)u1[0]; f0[5] = (__bf16)u1[1]; f0[6] = (__bf16)u1[2]; f0[7] = (__bf16)u1[3];
      *(bf16x8_t*)&Atile[kt_st][lanep_st][0] = f0;
    }
    __syncthreads();

    // ---- MFMA: P[16 rows][this wave's 32 cols] ----
    floatx4_t acc[2];
    acc[0] = (floatx4_t){0.f, 0.f, 0.f, 0.f};
    acc[1] = (floatx4_t){0.f, 0.f, 0.f, 0.f};
    #pragma unroll
    for (int kt = 0; kt < 4; kt++) {
      bf16x8_t af = *(const bf16x8_t*)&Atile[kt][lane][0];
      acc[0] = __builtin_amdgcn_mfma_f32_16x16x32_bf16(af, breg[0][kt], acc[0], 0, 0, 0);
      acc[1] = __builtin_amdgcn_mfma_f32_16x16x32_bf16(af, breg[1][kt], acc[1], 0, 0, 0);
    }

    // ---- residual: exact fp32 from global (L1/L2 hits on just-fetched rows).
    // C/D layout: row = quad*4 + i2, col = wave*32 + n2*16 + m.
    // x1[s] == y[s+1] -> 5 row-loads cover 4 residual rows. ----
    int s0 = ((rt & 63) << 4) + (quad << 2); // seq position of i2=0 (64 tiles/batch)
    size_t gr = row0 + (quad << 2);
    #pragma unroll
    for (int n2 = 0; n2 < 2; n2++) {
      int c = (wave << 5) + (n2 << 4) + m;
      float yv[5];
      #pragma unroll
      for (int t = 0; t < 5; t++) {
        size_t r = gr + t;
        if (r > (size_t)(NROWS_TOTAL - 1)) r = (size_t)(NROWS_TOTAL - 1);
        yv[t] = x[(r << 7) + c];
      }
      #pragma unroll
      for (int i2 = 0; i2 < 4; i2++) {
        if (s0 + i2 <= SEQ - 2) {
          float rr = (yv[i2] - yv[i2 + 1]) + acc[n2][i2];
          lsum += rr * rr;
        }
      }
    }
    __syncthreads();                         // protect Atile before next stage
  }

  #pragma unroll
  for (int off = 32; off > 0; off >>= 1) lsum += __shfl_down(lsum, off);
  __shared__ float red[4];
  if (lane == 0) red[wave] = lsum;
  __syncthreads();
  if (tid == 0) atomicAdd(accum, red[0] + red[1] + red[2] + red[3]);
}

__global__ void finalize_kernel(const float* __restrict__ accum, float* __restrict__ out) {
  out[0] = accum[0] * (1.0f / STEP_ELEMS) + 0.001f * accum[1] * (1.0f / 16384.0f);
}

extern "C" void kernel_launch(void* const* d_in, const int* in_sizes, int n_in,
                              void* d_out, int out_size, void* d_ws, size_t ws_size,
                              hipStream_t stream) {
  const float* x = (const float*)d_in[0];
  const float* C = (const float*)d_in[1];
  __bf16* Dpack = (__bf16*)d_ws;
  float* accum = (float*)((char*)d_ws + 32768);
  float* T = (float*)((char*)d_ws + 65536);
  float* out = (float*)d_out;

  prep_p1<<<64, 256, 0, stream>>>(C, T, accum);
  prep_p2<<<64, 256, 0, stream>>>(C, T, Dpack);
  sindy_main<<<GRID, 256, 0, stream>>>(x, Dpack, accum);
  finalize_kernel<<<1, 1, 0, stream>>>(accum, out);
}